// Round 8
// baseline (486.040 us; speedup 1.0000x reference)
//
#include <hip/hip_runtime.h>

#define D_    784
#define ROWS  8               // rows per block; feature = 8 dwords + 4 pad
#define NCLS  10
#define BLOCK 256             // 4 waves; 2 blocks/CU at 75.6 KB LDS
#define NB    (65536 / ROWS)  // 8192 blocks
#define HSTR  12              // dword stride per feature (48 B, 16B-aligned)

// tanh-approx GELU (|err| vs exact erf-GELU ~5e-4)
__device__ __forceinline__ float gelu_f(float x) {
    float x2    = x * x;
    float inner = fmaf(0.044715f * x, x2, x);
    float e     = exp2f(2.3022082f * inner);          // 2*sqrt(2/pi)*log2(e)
    float r     = __builtin_amdgcn_rcpf(e + 1.0f);
    return fmaf(-x, r, x);                            // x*e/(e+1)
}

__device__ __forceinline__ void fma4(float4& a, const float4& h4, float wk) {
    a.x = fmaf(h4.x, wk, a.x);
    a.y = fmaf(h4.y, wk, a.y);
    a.z = fmaf(h4.z, wk, a.z);
    a.w = fmaf(h4.w, wk, a.w);
}

template <int K>
__device__ __forceinline__ void loadIdxW(const int* __restrict__ idx,
                                         const float* __restrict__ w,
                                         int n, int* jc, float* wc) {
    if constexpr (K == 2) {
        int2   j = *(const int2*)(idx + n * 2);
        float2 v = *(const float2*)(w + n * 2);
        jc[0] = j.x; jc[1] = j.y; wc[0] = v.x; wc[1] = v.y;
    } else if constexpr (K == 4) {
        int4   j = *(const int4*)(idx + n * 4);
        float4 v = *(const float4*)(w + n * 4);
        jc[0] = j.x; jc[1] = j.y; jc[2] = j.z; jc[3] = j.w;
        wc[0] = v.x; wc[1] = v.y; wc[2] = v.z; wc[3] = v.w;
    } else {
        int4   ja = *(const int4*)(idx + n * 8);
        int4   jb = *(const int4*)(idx + n * 8 + 4);
        float4 va = *(const float4*)(w + n * 8);
        float4 vb = *(const float4*)(w + n * 8 + 4);
        jc[0] = ja.x; jc[1] = ja.y; jc[2] = ja.z; jc[3] = ja.w;
        jc[4] = jb.x; jc[5] = jb.y; jc[6] = jb.z; jc[7] = jb.w;
        wc[0] = va.x; wc[1] = va.y; wc[2] = va.z; wc[3] = va.w;
        wc[4] = vb.x; wc[5] = vb.y; wc[6] = vb.z; wc[7] = vb.w;
    }
}

// Ping-pong sparse layer, ONE thread per feature (all 8 rows).
// Per (n,k): 1 addr + 2 ds_read_b128 (offset imm) + 8 fma.
template <int K>
__device__ __forceinline__ void layer_fn(const float* __restrict__ src,
                                         float* __restrict__ dst,
                                         const int* __restrict__ idx,
                                         const float* __restrict__ w,
                                         const float* __restrict__ bias,
                                         int tid) {
    int   jc[K];
    float wc[K];
    float bc;
    loadIdxW<K>(idx, w, tid, jc, wc);     // i = 0 always valid (tid < 784)
    bc = bias[tid];
#pragma unroll 1
    for (int i = 0; i < 4; ++i) {
        int n  = tid + 256 * i;
        int nn = n + 256;
        int   jn[K]; float wn[K]; float bn = 0.f;
#pragma unroll
        for (int k = 0; k < K; ++k) { jn[k] = 0; wn[k] = 0.f; }
        if (nn < D_) {                    // prefetch i+1 while computing i
            loadIdxW<K>(idx, w, nn, jn, wn);
            bn = bias[nn];
        }
        if (n < D_) {
            float4 aL = make_float4(bc, bc, bc, bc);
            float4 aH = make_float4(bc, bc, bc, bc);
#pragma unroll
            for (int k = 0; k < K; ++k) {
                const float* hb = src + jc[k] * HSTR;
                float4 h0 = *(const float4*)(hb);
                float4 h1 = *(const float4*)(hb + 4);
                fma4(aL, h0, wc[k]);
                fma4(aH, h1, wc[k]);
            }
            float* db = dst + n * HSTR;
            *(float4*)(db)     = make_float4(gelu_f(aL.x), gelu_f(aL.y),
                                             gelu_f(aL.z), gelu_f(aL.w));
            *(float4*)(db + 4) = make_float4(gelu_f(aH.x), gelu_f(aH.y),
                                             gelu_f(aH.z), gelu_f(aH.w));
        }
#pragma unroll
        for (int k = 0; k < K; ++k) { jc[k] = jn[k]; wc[k] = wn[k]; }
        bc = bn;
    }
    __syncthreads();
}

__global__ __launch_bounds__(BLOCK)
void circnn_kernel(const float* __restrict__ x,
                   const int* __restrict__ idx1, const float* __restrict__ w1, const float* __restrict__ b1,
                   const int* __restrict__ idx2, const float* __restrict__ w2, const float* __restrict__ b2,
                   const int* __restrict__ idx3, const float* __restrict__ w3, const float* __restrict__ b3,
                   const float* __restrict__ fcw, const float* __restrict__ fcb,
                   float* __restrict__ out) {
    __shared__ __align__(16) float bufA[D_ * HSTR];   // 37,632 B: x, h2; FC partials
    __shared__ __align__(16) float bufB[D_ * HSTR];   // 37,632 B: h1, h3
    __shared__ float logits[ROWS * NCLS];             // 320 B

    const int tid  = threadIdx.x;
    const int row0 = blockIdx.x * ROWS;

    // ---- Stage x -> bufA: 8 strided-coalesced b32 reads -> 2 b128 writes.
    // Write banks: starts (12n)&31 tile all 32 banks over 8 positions -> conflict-free.
    const float* xb = x + (size_t)row0 * D_;
#pragma unroll 1
    for (int i = 0; i < 4; ++i) {
        int n = tid + 256 * i;
        if (n < D_) {
            float4 v0, v1;
            v0.x = xb[0 * D_ + n]; v0.y = xb[1 * D_ + n];
            v0.z = xb[2 * D_ + n]; v0.w = xb[3 * D_ + n];
            v1.x = xb[4 * D_ + n]; v1.y = xb[5 * D_ + n];
            v1.z = xb[6 * D_ + n]; v1.w = xb[7 * D_ + n];
            float* db = bufA + n * HSTR;
            *(float4*)(db)     = v0;
            *(float4*)(db + 4) = v1;
        }
    }
    __syncthreads();

    // ---- Three sparse layers, ping-pong: A->B->A->B
    layer_fn<2>(bufA, bufB, idx1, w1, b1, tid);
    layer_fn<4>(bufB, bufA, idx2, w2, b2, tid);
    layer_fn<8>(bufA, bufB, idx3, w3, b3, tid);

    // ---- FC phase A: 128 threads, partials into bufA (free). No shuffles.
    float4* part4 = (float4*)bufA;    // layout [(jj*2+qq)*NCLS + c], 10,240 B
    if (tid < 128) {
        const int jj = tid >> 1;      // 0..63
        const int qq = tid & 1;       // row quad
        float4 facc[NCLS];
#pragma unroll
        for (int c = 0; c < NCLS; ++c) facc[c] = make_float4(0.f, 0.f, 0.f, 0.f);
#pragma unroll 1
        for (int i = 0; i < 13; ++i) {
            int n = jj + 64 * i;
            if (n < D_) {
                float4 hv = *(const float4*)(bufB + n * HSTR + qq * 4);
#pragma unroll
                for (int c = 0; c < NCLS; ++c)
                    fma4(facc[c], hv, fcw[c * D_ + n]);
            }
        }
#pragma unroll
        for (int c = 0; c < NCLS; ++c)
            part4[(jj * 2 + qq) * NCLS + c] = facc[c];
    }
    __syncthreads();

    // ---- FC phase B: 80 threads (r, c) sum 64 partials -> logits
    if (tid < ROWS * NCLS) {
        int r = tid / NCLS, c = tid - r * NCLS;
        int qq = r >> 2, comp = r & 3;
        const float* pf = (const float*)part4;
        float s = fcb[c];
#pragma unroll 4
        for (int jj = 0; jj < 64; ++jj)
            s += pf[((jj * 2 + qq) * NCLS + c) * 4 + comp];
        logits[tid] = s;
    }
    __syncthreads();

    // ---- softmax (redundant per-(r,c) thread), coalesced 80-float store
    if (tid < ROWS * NCLS) {
        int r = tid / NCLS;
        const float* lg = logits + r * NCLS;
        float m = lg[0];
#pragma unroll
        for (int c = 1; c < NCLS; ++c) m = fmaxf(m, lg[c]);
        float s = 0.f;
#pragma unroll
        for (int c = 0; c < NCLS; ++c) s += __expf(lg[c] - m);
        out[(size_t)row0 * NCLS + tid] = __expf(logits[tid] - m) / s;
    }
}

extern "C" void kernel_launch(void* const* d_in, const int* in_sizes, int n_in,
                              void* d_out, int out_size, void* d_ws, size_t ws_size,
                              hipStream_t stream) {
    const float* x    = (const float*)d_in[0];
    const int*   idx1 = (const int*)d_in[1];
    const float* w1   = (const float*)d_in[2];
    const float* b1   = (const float*)d_in[3];
    const int*   idx2 = (const int*)d_in[4];
    const float* w2   = (const float*)d_in[5];
    const float* b2   = (const float*)d_in[6];
    const int*   idx3 = (const int*)d_in[7];
    const float* w3   = (const float*)d_in[8];
    const float* b3   = (const float*)d_in[9];
    const float* fcw  = (const float*)d_in[10];
    const float* fcb  = (const float*)d_in[11];
    float* out = (float*)d_out;

    circnn_kernel<<<dim3(NB), dim3(BLOCK), 0, stream>>>(
        x, idx1, w1, b1, idx2, w2, b2, idx3, w3, b3, fcw, fcb, out);
}